// Round 5
// baseline (488.764 us; speedup 1.0000x reference)
//
#include <hip/hip_runtime.h>

typedef __bf16 bf16;
typedef __bf16 bf16x4 __attribute__((ext_vector_type(4)));
typedef __bf16 bf16x8 __attribute__((ext_vector_type(8)));
typedef float f32x4 __attribute__((ext_vector_type(4)));

#define T_SEQ 2048
#define QK_LD 2048

extern "C" __device__ float __ocml_native_exp2_f32(float);   // raw v_exp_f32

// ---------------------------------------------------------------------------
// Prep kernels
// ---------------------------------------------------------------------------
__global__ void cvt_f32_bf16(const float* __restrict__ X, bf16* __restrict__ Y, int n) {
    int i = (blockIdx.x * 256 + threadIdx.x) * 4;
    if (i >= n) return;
    const float4 f = *(const float4*)(X + i);
    bf16x4 o;
    o.x = (bf16)f.x; o.y = (bf16)f.y; o.z = (bf16)f.z; o.w = (bf16)f.w;
    *(bf16x4*)(Y + i) = o;
}

// W[R][C] fp32 (row-major) -> Wt[C][R] bf16
__global__ void transpose_cvt(const float* __restrict__ W, bf16* __restrict__ Wt,
                              int R, int C) {
    __shared__ float tile[32][33];
    const int bx = blockIdx.x * 32;
    const int by = blockIdx.y * 32;
    const int tx = threadIdx.x, ty = threadIdx.y;
#pragma unroll
    for (int i = 0; i < 32; i += 8)
        tile[ty + i][tx] = W[(size_t)(by + ty + i) * C + bx + tx];
    __syncthreads();
#pragma unroll
    for (int i = 0; i < 32; i += 8)
        Wt[(size_t)(bx + ty + i) * R + by + tx] = (bf16)tile[tx][ty + i];
}

// ---------------------------------------------------------------------------
// GEMM: C[M,N] = A[M,K]*Bt[N,K]^T (+bias). bf16 in, fp32 acc.
// 128x128 tile, BK=32, 256 thr. REGISTER staging (global->VGPR->ds_write),
// two rotating register sets = distance-2 prefetch (~2 phases of latency
// cover, decoupled from the barrier's vmcnt drain). Single barrier/phase,
// 2 LDS buffers. Global loads linear; XOR swizzle applied at the LDS-write
// address (chunk c of row r -> slot c^((r>>1)&3)); frag ds_read_b128 and
// staging ds_write_b128 both cover 64 distinct 16B slots (conflict-free).
// ---------------------------------------------------------------------------
template <bool OUT_BF16, bool SPLIT_V>
__global__ __launch_bounds__(256, 4)
void gemm_bt(const bf16* __restrict__ A, const bf16* __restrict__ Bt,
             const float* __restrict__ bias, void* __restrict__ Cout,
             bf16* __restrict__ Vtb, int M, int N, int K, int ldC) {
    __shared__ bf16 sm[16384];   // 2 bufs x (A 4096 + B 4096 elems) = 32 KB

    const int t = threadIdx.x;
    const int lane = t & 63, quad = lane >> 4, l16 = lane & 15;
    const int wave = t >> 6;
    const int wm = (wave >> 1) * 64;
    const int wn = (wave & 1) * 64;
    const long m0 = (long)blockIdx.y * 128;
    const long n0 = (long)blockIdx.x * 128;

    f32x4 acc[4][4] = {};

    // staging: thread t <-> (row sr = t>>2 in [0,64), chunk sc = t&3), + row sr+64
    const int sr = t >> 2, sc = t & 3;
    const int swz  = (sr * 4 + (sc ^ ((sr >> 1) & 3))) * 8;          // row sr
    const int swz2 = ((sr + 64) * 4 + (sc ^ ((sr >> 1) & 3))) * 8;   // row sr+64 (same xor)
    const bf16* agp = A  + (m0 + sr) * (long)K + sc * 8;
    const bf16* bgp = Bt + (n0 + sr) * (long)K + sc * 8;
    const long rowK = (long)64 * K;

    // frag read offsets (loop-invariant)
    int offA[4], offB[4];
#pragma unroll
    for (int i = 0; i < 4; ++i) {
        const int row = wm + i * 16 + l16;
        offA[i] = (row * 4 + (quad ^ ((row >> 1) & 3))) * 8;
    }
#pragma unroll
    for (int j = 0; j < 4; ++j) {
        const int row = wn + j * 16 + l16;
        offB[j] = 4096 + (row * 4 + (quad ^ ((row >> 1) & 3))) * 8;
    }

    uint4 Ra0[2], Ra1[2], Rb0[2], Rb1[2];   // two rotating staging sets

    auto load_set = [&](int s, int k) {
        Ra0[s] = *(const uint4*)(agp + k);
        Ra1[s] = *(const uint4*)(agp + rowK + k);
        Rb0[s] = *(const uint4*)(bgp + k);
        Rb1[s] = *(const uint4*)(bgp + rowK + k);
    };
    auto write_set = [&](int s, int buf) {
        bf16* base = &sm[buf * 8192];
        *(uint4*)(base + swz)         = Ra0[s];
        *(uint4*)(base + swz2)        = Ra1[s];
        *(uint4*)(base + 4096 + swz)  = Rb0[s];
        *(uint4*)(base + 4096 + swz2) = Rb1[s];
    };
    auto compute = [&](int buf) {
        const bf16* s = &sm[buf * 8192];
        bf16x8 af[4], bfr[4];
#pragma unroll
        for (int i = 0; i < 4; ++i) af[i] = *(const bf16x8*)(s + offA[i]);
#pragma unroll
        for (int j = 0; j < 4; ++j) bfr[j] = *(const bf16x8*)(s + offB[j]);
#pragma unroll
        for (int i = 0; i < 4; ++i)
#pragma unroll
            for (int j = 0; j < 4; ++j)   // swapped: D row=n, col=m
                acc[i][j] = __builtin_amdgcn_mfma_f32_16x16x32_bf16(bfr[j], af[i], acc[i][j], 0, 0, 0);
    };

    const int nk = K >> 5;      // BK=32 phases
    // prologue: set0 <- t0, set1 <- t1; publish t0; set0 begins loading t2
    load_set(0, 0);
    load_set(1, 32);
    write_set(0, 0);
    load_set(0, 64);
    __syncthreads();

    for (int kk = 0; kk < nk; ++kk) {
        // entry: buf[kk&1] published; set[(kk+1)&1] holds tile kk+1;
        //        set[kk&1] is in-flight with tile kk+2
        if (kk + 1 < nk) {
            write_set((kk + 1) & 1, (kk + 1) & 1);
            if (kk + 3 < nk) load_set((kk + 1) & 1, (kk + 3) * 32);
        }
        compute(kk & 1);
        if (kk + 1 < nk) __syncthreads();
    }

    // epilogue: lane holds m = wm+i*16+l16, n = wn+j*16+quad*4+r
    bf16*  Cb = (bf16*)Cout;
    float* Cf = (float*)Cout;
    const bool vblock = SPLIT_V && (n0 >= 2048);
#pragma unroll
    for (int i = 0; i < 4; ++i) {
        const long gm = m0 + wm + i * 16 + l16;
#pragma unroll
        for (int j = 0; j < 4; ++j) {
            const int nloc = wn + j * 16 + quad * 4;
            const long n = n0 + nloc;
            const float4 bv = *(const float4*)(bias + n);
            float v[4];
#pragma unroll
            for (int r = 0; r < 4; ++r) v[r] = acc[i][j][r] + (&bv.x)[r];
            if (vblock) {
                const int bb = (int)(gm >> 11), tok = (int)(gm & 2047);
                const int nv = (int)(n - 2048);
                const int h = nv >> 6, d0 = nv & 63;
                bf16* dst = Vtb + ((size_t)(bb * 16 + h) * 64 + d0) * T_SEQ + tok;
#pragma unroll
                for (int r = 0; r < 4; ++r) dst[(size_t)r * T_SEQ] = (bf16)v[r];
            } else if (OUT_BF16) {
                bf16x4 o;
#pragma unroll
                for (int r = 0; r < 4; ++r) o[r] = (bf16)v[r];
                *(bf16x4*)(Cb + gm * ldC + n) = o;
            } else {
                float4 o;
#pragma unroll
                for (int r = 0; r < 4; ++r) (&o.x)[r] = v[r];
                *(float4*)(Cf + gm * ldC + n) = o;
            }
        }
    }
}

// ---------------------------------------------------------------------------
// Causal flash attention (unchanged from round 4 — validated).
// ---------------------------------------------------------------------------
__global__ __launch_bounds__(256, 3)
void attn_kernel(const bf16* __restrict__ qk, const bf16* __restrict__ vtb,
                 bf16* __restrict__ Out) {
    const int bh = blockIdx.x;
    const int qt = 15 - (int)blockIdx.y;    // heavy tiles first
    const int b = bh >> 4, h = bh & 15;
    const int t = threadIdx.x;
    const int wave = t >> 6, lane = t & 63, quad = lane >> 4, l16 = lane & 15;
    const int wq = wave * 32;
    const int q0 = qt * 128;

    __shared__ bf16 Ks[2][4096];
    __shared__ bf16 VTs[2][4096];
    __shared__ bf16 Ps[8192];

    const bf16* Qg = qk + (size_t)b * T_SEQ * QK_LD + h * 64;
    const bf16* Kg = Qg + 1024;
    const bf16* vth = vtb + (size_t)bh * 64 * T_SEQ;

    for (int c = t; c < 1024; c += 256) {
        const int row = c >> 3, kb = c & 7;
        *(uint4*)(Ps + row * 64 + (((kb ^ (row & 7)) << 3))) =
            *(const uint4*)(Qg + (size_t)(q0 + row) * QK_LD + kb * 8);
    }
    __syncthreads();
    const float qsc = 0.125f * 1.4426950408889634f;
    bf16x8 qf[2][2];
#pragma unroll
    for (int jt = 0; jt < 2; ++jt)
#pragma unroll
        for (int s = 0; s < 2; ++s) {
            const int row = wq + jt * 16 + l16;
            bf16x8 v = *(const bf16x8*)(Ps + row * 64 + (((s * 4 + quad) ^ (row & 7)) << 3));
#pragma unroll
            for (int e = 0; e < 8; ++e) v[e] = (bf16)((float)v[e] * qsc);
            qf[jt][s] = v;
        }

    const int sr = t >> 3;
    const int skb = (t & 7) ^ (sr & 7);
    const bf16* kp0 = Kg + (size_t)sr * QK_LD + skb * 8;
    const bf16* kp1 = kp0 + (size_t)32 * QK_LD;
    const bf16* vp0 = vth + (size_t)sr * T_SEQ + skb * 8;
    const bf16* vp1 = vp0 + (size_t)32 * T_SEQ;

    int offKV[4][2];
#pragma unroll
    for (int it = 0; it < 4; ++it)
#pragma unroll
        for (int s = 0; s < 2; ++s) {
            const int row = it * 16 + l16;
            offKV[it][s] = row * 64 + (((s * 4 + quad) ^ (row & 7)) << 3);
        }

    f32x4 oacc[4][2] = {};
    float lsum[2] = {0.f, 0.f};
    const int nkt = qt * 2 + 2;

    uint4 kr0 = *(const uint4*)kp0, kr1 = *(const uint4*)kp1;
    uint4 vr0 = *(const uint4*)vp0, vr1 = *(const uint4*)vp1;

    for (int kt = 0; kt < nkt; ++kt) {
        const int k0 = kt * 64;
        bf16* kb_ = Ks[kt & 1];
        bf16* vb_ = VTs[kt & 1];
        *(uint4*)(kb_ + t * 8)        = kr0;
        *(uint4*)(kb_ + 2048 + t * 8) = kr1;
        *(uint4*)(vb_ + t * 8)        = vr0;
        *(uint4*)(vb_ + 2048 + t * 8) = vr1;
        __syncthreads();

        if (kt + 1 < nkt) {
            const int kn = k0 + 64;
            kr0 = *(const uint4*)(kp0 + (size_t)kn * QK_LD);
            kr1 = *(const uint4*)(kp1 + (size_t)kn * QK_LD);
            vr0 = *(const uint4*)(vp0 + kn);
            vr1 = *(const uint4*)(vp1 + kn);
        }

        f32x4 sacc[4][2] = {};
#pragma unroll
        for (int s = 0; s < 2; ++s) {
            bf16x8 kf[4];
#pragma unroll
            for (int it = 0; it < 4; ++it)
                kf[it] = *(const bf16x8*)(kb_ + offKV[it][s]);
#pragma unroll
            for (int it = 0; it < 4; ++it)
#pragma unroll
                for (int jt = 0; jt < 2; ++jt)
                    sacc[it][jt] = __builtin_amdgcn_mfma_f32_16x16x32_bf16(kf[it], qf[jt][s], sacc[it][jt], 0, 0, 0);
        }

        const bool need_mask = (kt >= 2 * qt);
#pragma unroll
        for (int it = 0; it < 4; ++it)
#pragma unroll
            for (int jt = 0; jt < 2; ++jt) {
                const int prow = wq + jt * 16 + l16;
                bf16x4 pb;
                if (need_mask) {
                    const int qrow = q0 + prow;
                    const int kbase = k0 + it * 16 + quad * 4;
#pragma unroll
                    for (int r = 0; r < 4; ++r) {
                        const float e = __ocml_native_exp2_f32(sacc[it][jt][r]);
                        const float p = (kbase + r > qrow) ? 0.f : e;
                        lsum[jt] += p;
                        pb[r] = (bf16)p;
                    }
                } else {
#pragma unroll
                    for (int r = 0; r < 4; ++r) {
                        const float p = __ocml_native_exp2_f32(sacc[it][jt][r]);
                        lsum[jt] += p;
                        pb[r] = (bf16)p;
                    }
                }
                *(bf16x4*)(Ps + prow * 64 +
                           (((it * 2 + (quad >> 1)) ^ (prow & 7)) << 3) + ((quad & 1) << 2)) = pb;
            }

#pragma unroll
        for (int s2 = 0; s2 < 2; ++s2) {
            bf16x8 vf[4], pf[2];
#pragma unroll
            for (int it2 = 0; it2 < 4; ++it2)
                vf[it2] = *(const bf16x8*)(vb_ + offKV[it2][s2]);
#pragma unroll
            for (int jt = 0; jt < 2; ++jt) {
                const int prow = wq + jt * 16 + l16;
                pf[jt] = *(const bf16x8*)(Ps + prow * 64 + (((s2 * 4 + quad) ^ (prow & 7)) << 3));
            }
#pragma unroll
            for (int it2 = 0; it2 < 4; ++it2)
#pragma unroll
                for (int jt = 0; jt < 2; ++jt)
                    oacc[it2][jt] = __builtin_amdgcn_mfma_f32_16x16x32_bf16(vf[it2], pf[jt], oacc[it2][jt], 0, 0, 0);
        }
    }

    float inv[2];
#pragma unroll
    for (int jt = 0; jt < 2; ++jt) {
        float l = lsum[jt];
        l += __shfl_xor(l, 16);
        l += __shfl_xor(l, 32);
        inv[jt] = 1.0f / l;
    }
#pragma unroll
    for (int it2 = 0; it2 < 4; ++it2)
#pragma unroll
        for (int jt = 0; jt < 2; ++jt) {
            bf16x4 ob;
#pragma unroll
            for (int r = 0; r < 4; ++r) ob[r] = (bf16)(oacc[it2][jt][r] * inv[jt]);
            const int qrow = q0 + wq + jt * 16 + l16;
            const int dcol = h * 64 + it2 * 16 + quad * 4;
            *(bf16x4*)&Out[(size_t)(b * T_SEQ + qrow) * 1024 + dcol] = ob;
        }
}

// ---------------------------------------------------------------------------
extern "C" void kernel_launch(void* const* d_in, const int* in_sizes, int n_in,
                              void* d_out, int out_size, void* d_ws, size_t ws_size,
                              hipStream_t stream) {
    const float* x     = (const float*)d_in[0];
    const float* W_qkv = (const float*)d_in[1];
    const float* b_qkv = (const float*)d_in[2];
    const float* W_out = (const float*)d_in[3];
    const float* b_out = (const float*)d_in[4];
    float* out = (float*)d_out;

    char* ws = (char*)d_ws;
    bf16* xb   = (bf16*)ws; ws += (size_t)8192 * 1024 * 2;
    bf16* wtq  = (bf16*)ws; ws += (size_t)3072 * 1024 * 2;
    bf16* wto  = (bf16*)ws; ws += (size_t)1024 * 1024 * 2;
    bf16* qkb  = (bf16*)ws; ws += (size_t)8192 * 2048 * 2;    // Q|K rows
    bf16* vtb  = (bf16*)ws; ws += (size_t)64 * 64 * 2048 * 2; // V^T per bh
    bf16* aout = (bf16*)ws; ws += (size_t)8192 * 1024 * 2;

    cvt_f32_bf16<<<8192, 256, 0, stream>>>(x, xb, 8192 * 1024);
    transpose_cvt<<<dim3(96, 32), dim3(32, 8), 0, stream>>>(W_qkv, wtq, 1024, 3072);
    transpose_cvt<<<dim3(32, 32), dim3(32, 8), 0, stream>>>(W_out, wto, 1024, 1024);

    gemm_bt<true, true><<<dim3(24, 64), 256, 0, stream>>>(
        xb, wtq, b_qkv, (void*)qkb, vtb, 8192, 3072, 1024, 2048);
    attn_kernel<<<dim3(64, 16), 256, 0, stream>>>(qkb, vtb, aout);
    gemm_bt<false, false><<<dim3(8, 64), 256, 0, stream>>>(
        aout, wto, b_out, (void*)out, nullptr, 8192, 1024, 1024, 1024);
}

// Round 6
// 247.520 us; speedup vs baseline: 1.9746x; 1.9746x over previous
//
#include <hip/hip_runtime.h>

typedef __bf16 bf16;
typedef __bf16 bf16x4 __attribute__((ext_vector_type(4)));
typedef __bf16 bf16x8 __attribute__((ext_vector_type(8)));
typedef float f32x4 __attribute__((ext_vector_type(4)));

#define T_SEQ 2048
#define QK_LD 2048

extern "C" __device__ float __ocml_native_exp2_f32(float);   // raw v_exp_f32

// ---------------------------------------------------------------------------
// Prep kernels
// ---------------------------------------------------------------------------
__global__ void cvt_f32_bf16(const float* __restrict__ X, bf16* __restrict__ Y, int n) {
    int i = (blockIdx.x * 256 + threadIdx.x) * 4;
    if (i >= n) return;
    const float4 f = *(const float4*)(X + i);
    bf16x4 o;
    o.x = (bf16)f.x; o.y = (bf16)f.y; o.z = (bf16)f.z; o.w = (bf16)f.w;
    *(bf16x4*)(Y + i) = o;
}

// W[R][C] fp32 (row-major) -> Wt[C][R] bf16
__global__ void transpose_cvt(const float* __restrict__ W, bf16* __restrict__ Wt,
                              int R, int C) {
    __shared__ float tile[32][33];
    const int bx = blockIdx.x * 32;
    const int by = blockIdx.y * 32;
    const int tx = threadIdx.x, ty = threadIdx.y;
#pragma unroll
    for (int i = 0; i < 32; i += 8)
        tile[ty + i][tx] = W[(size_t)(by + ty + i) * C + bx + tx];
    __syncthreads();
#pragma unroll
    for (int i = 0; i < 32; i += 8)
        Wt[(size_t)(bx + ty + i) * R + by + tx] = (bf16)tile[tx][ty + i];
}

// ---------------------------------------------------------------------------
// GEMM: C[M,N] = A[M,K]*Bt[N,K]^T (+bias). bf16 in, fp32 acc.
// 128x128 tile, BK=32, 256 thr. Register staging (global->VGPR->ds_write)
// with TWO STATICALLY-NAMED register sets (no dynamic indexing -> no scratch
// spill; round-5's array-indexed version spilled: WRITE_SIZE 789 MB).
// K-loop unrolled x2: each half references a fixed set + fixed LDS buffer.
// Distance-2 prefetch: the set published in phase kk was loaded in kk-2
// (~2 phases of latency cover); its reload targets tile kk+3. Single
// barrier per phase; compiler can wait vmcnt(4) (publish set only) while
// the other set's 4 loads stay in flight.
// ---------------------------------------------------------------------------
template <bool OUT_BF16, bool SPLIT_V>
__global__ __launch_bounds__(256, 3)
void gemm_bt(const bf16* __restrict__ A, const bf16* __restrict__ Bt,
             const float* __restrict__ bias, void* __restrict__ Cout,
             bf16* __restrict__ Vtb, int M, int N, int K, int ldC) {
    __shared__ bf16 sm[16384];   // 2 bufs x (A 4096 + B 4096 elems) = 32 KB

    const int t = threadIdx.x;
    const int lane = t & 63, quad = lane >> 4, l16 = lane & 15;
    const int wave = t >> 6;
    const int wm = (wave >> 1) * 64;
    const int wn = (wave & 1) * 64;
    const long m0 = (long)blockIdx.y * 128;
    const long n0 = (long)blockIdx.x * 128;

    f32x4 acc[4][4] = {};

    // staging: thread t <-> (row sr = t>>2 in [0,64), chunk sc = t&3), + row sr+64
    const int sr = t >> 2, sc = t & 3;
    const int swz  = (sr * 4 + (sc ^ ((sr >> 1) & 3))) * 8;          // row sr
    const int swz2 = ((sr + 64) * 4 + (sc ^ ((sr >> 1) & 3))) * 8;   // row sr+64
    const bf16* agp = A  + (m0 + sr) * (long)K + sc * 8;
    const bf16* bgp = Bt + (n0 + sr) * (long)K + sc * 8;
    const long rowK = (long)64 * K;

    // frag read offsets (loop-invariant)
    int offA[4], offB[4];
#pragma unroll
    for (int i = 0; i < 4; ++i) {
        const int row = wm + i * 16 + l16;
        offA[i] = (row * 4 + (quad ^ ((row >> 1) & 3))) * 8;
    }
#pragma unroll
    for (int j = 0; j < 4; ++j) {
        const int row = wn + j * 16 + l16;
        offB[j] = 4096 + (row * 4 + (quad ^ ((row >> 1) & 3))) * 8;
    }

    // two statically-named staging sets (kept in VGPRs)
    uint4 s0a0, s0a1, s0b0, s0b1;
    uint4 s1a0, s1a1, s1b0, s1b1;

    auto load0 = [&](int k) {
        s0a0 = *(const uint4*)(agp + k);        s0a1 = *(const uint4*)(agp + rowK + k);
        s0b0 = *(const uint4*)(bgp + k);        s0b1 = *(const uint4*)(bgp + rowK + k);
    };
    auto load1 = [&](int k) {
        s1a0 = *(const uint4*)(agp + k);        s1a1 = *(const uint4*)(agp + rowK + k);
        s1b0 = *(const uint4*)(bgp + k);        s1b1 = *(const uint4*)(bgp + rowK + k);
    };
    auto write0 = [&]() {   // always buf0
        *(uint4*)(sm + swz)         = s0a0;  *(uint4*)(sm + swz2)        = s0a1;
        *(uint4*)(sm + 4096 + swz)  = s0b0;  *(uint4*)(sm + 4096 + swz2) = s0b1;
    };
    auto write1 = [&]() {   // always buf1
        bf16* base = sm + 8192;
        *(uint4*)(base + swz)         = s1a0;  *(uint4*)(base + swz2)        = s1a1;
        *(uint4*)(base + 4096 + swz)  = s1b0;  *(uint4*)(base + 4096 + swz2) = s1b1;
    };
    auto compute = [&](const bf16* s) {
        bf16x8 af[4], bfr[4];
#pragma unroll
        for (int i = 0; i < 4; ++i) af[i] = *(const bf16x8*)(s + offA[i]);
#pragma unroll
        for (int j = 0; j < 4; ++j) bfr[j] = *(const bf16x8*)(s + offB[j]);
#pragma unroll
        for (int i = 0; i < 4; ++i)
#pragma unroll
            for (int j = 0; j < 4; ++j)   // swapped: D row=n, col=m
                acc[i][j] = __builtin_amdgcn_mfma_f32_16x16x32_bf16(bfr[j], af[i], acc[i][j], 0, 0, 0);
    };

    const int nk = K >> 5;   // BK=32 phases (32 for K=1024)
    // prologue: set0 <- tile0, set1 <- tile1; publish tile0; set0 <- tile2
    load0(0);
    load1(32);
    write0();
    load0(64);
    __syncthreads();

    for (int kk = 0; kk < nk; kk += 2) {
        // phase kk (even): compute buf0=tile kk; publish set1 (tile kk+1) -> buf1
        if (kk + 1 < nk) {
            write1();
            if (kk + 3 < nk) load1((kk + 3) * 32);
        }
        compute(sm);
        if (kk + 1 < nk) {
            __syncthreads();
            // phase kk+1 (odd): compute buf1=tile kk+1; publish set0 (tile kk+2) -> buf0
            if (kk + 2 < nk) {
                write0();
                if (kk + 4 < nk) load0((kk + 4) * 32);
            }
            compute(sm + 8192);
            if (kk + 2 < nk) __syncthreads();
        }
    }

    // epilogue: lane holds m = wm+i*16+l16, n = wn+j*16+quad*4+r
    bf16*  Cb = (bf16*)Cout;
    float* Cf = (float*)Cout;
    const bool vblock = SPLIT_V && (n0 >= 2048);
#pragma unroll
    for (int i = 0; i < 4; ++i) {
        const long gm = m0 + wm + i * 16 + l16;
#pragma unroll
        for (int j = 0; j < 4; ++j) {
            const int nloc = wn + j * 16 + quad * 4;
            const long n = n0 + nloc;
            const float4 bv = *(const float4*)(bias + n);
            float v[4];
#pragma unroll
            for (int r = 0; r < 4; ++r) v[r] = acc[i][j][r] + (&bv.x)[r];
            if (vblock) {
                const int bb = (int)(gm >> 11), tok = (int)(gm & 2047);
                const int nv = (int)(n - 2048);
                const int h = nv >> 6, d0 = nv & 63;
                bf16* dst = Vtb + ((size_t)(bb * 16 + h) * 64 + d0) * T_SEQ + tok;
#pragma unroll
                for (int r = 0; r < 4; ++r) dst[(size_t)r * T_SEQ] = (bf16)v[r];
            } else if (OUT_BF16) {
                bf16x4 o;
#pragma unroll
                for (int r = 0; r < 4; ++r) o[r] = (bf16)v[r];
                *(bf16x4*)(Cb + gm * ldC + n) = o;
            } else {
                float4 o;
#pragma unroll
                for (int r = 0; r < 4; ++r) (&o.x)[r] = v[r];
                *(float4*)(Cf + gm * ldC + n) = o;
            }
        }
    }
}

// ---------------------------------------------------------------------------
// Causal flash attention (unchanged — validated at ~79 µs, round 4).
// ---------------------------------------------------------------------------
__global__ __launch_bounds__(256, 3)
void attn_kernel(const bf16* __restrict__ qk, const bf16* __restrict__ vtb,
                 bf16* __restrict__ Out) {
    const int bh = blockIdx.x;
    const int qt = 15 - (int)blockIdx.y;    // heavy tiles first
    const int b = bh >> 4, h = bh & 15;
    const int t = threadIdx.x;
    const int wave = t >> 6, lane = t & 63, quad = lane >> 4, l16 = lane & 15;
    const int wq = wave * 32;
    const int q0 = qt * 128;

    __shared__ bf16 Ks[2][4096];
    __shared__ bf16 VTs[2][4096];
    __shared__ bf16 Ps[8192];

    const bf16* Qg = qk + (size_t)b * T_SEQ * QK_LD + h * 64;
    const bf16* Kg = Qg + 1024;
    const bf16* vth = vtb + (size_t)bh * 64 * T_SEQ;

    for (int c = t; c < 1024; c += 256) {
        const int row = c >> 3, kb = c & 7;
        *(uint4*)(Ps + row * 64 + (((kb ^ (row & 7)) << 3))) =
            *(const uint4*)(Qg + (size_t)(q0 + row) * QK_LD + kb * 8);
    }
    __syncthreads();
    const float qsc = 0.125f * 1.4426950408889634f;
    bf16x8 qf[2][2];
#pragma unroll
    for (int jt = 0; jt < 2; ++jt)
#pragma unroll
        for (int s = 0; s < 2; ++s) {
            const int row = wq + jt * 16 + l16;
            bf16x8 v = *(const bf16x8*)(Ps + row * 64 + (((s * 4 + quad) ^ (row & 7)) << 3));
#pragma unroll
            for (int e = 0; e < 8; ++e) v[e] = (bf16)((float)v[e] * qsc);
            qf[jt][s] = v;
        }

    const int sr = t >> 3;
    const int skb = (t & 7) ^ (sr & 7);
    const bf16* kp0 = Kg + (size_t)sr * QK_LD + skb * 8;
    const bf16* kp1 = kp0 + (size_t)32 * QK_LD;
    const bf16* vp0 = vth + (size_t)sr * T_SEQ + skb * 8;
    const bf16* vp1 = vp0 + (size_t)32 * T_SEQ;

    int offKV[4][2];
#pragma unroll
    for (int it = 0; it < 4; ++it)
#pragma unroll
        for (int s = 0; s < 2; ++s) {
            const int row = it * 16 + l16;
            offKV[it][s] = row * 64 + (((s * 4 + quad) ^ (row & 7)) << 3);
        }

    f32x4 oacc[4][2] = {};
    float lsum[2] = {0.f, 0.f};
    const int nkt = qt * 2 + 2;

    uint4 kr0 = *(const uint4*)kp0, kr1 = *(const uint4*)kp1;
    uint4 vr0 = *(const uint4*)vp0, vr1 = *(const uint4*)vp1;

    for (int kt = 0; kt < nkt; ++kt) {
        const int k0 = kt * 64;
        bf16* kb_ = Ks[kt & 1];
        bf16* vb_ = VTs[kt & 1];
        *(uint4*)(kb_ + t * 8)        = kr0;
        *(uint4*)(kb_ + 2048 + t * 8) = kr1;
        *(uint4*)(vb_ + t * 8)        = vr0;
        *(uint4*)(vb_ + 2048 + t * 8) = vr1;
        __syncthreads();

        if (kt + 1 < nkt) {
            const int kn = k0 + 64;
            kr0 = *(const uint4*)(kp0 + (size_t)kn * QK_LD);
            kr1 = *(const uint4*)(kp1 + (size_t)kn * QK_LD);
            vr0 = *(const uint4*)(vp0 + kn);
            vr1 = *(const uint4*)(vp1 + kn);
        }

        f32x4 sacc[4][2] = {};
#pragma unroll
        for (int s = 0; s < 2; ++s) {
            bf16x8 kf[4];
#pragma unroll
            for (int it = 0; it < 4; ++it)
                kf[it] = *(const bf16x8*)(kb_ + offKV[it][s]);
#pragma unroll
            for (int it = 0; it < 4; ++it)
#pragma unroll
                for (int jt = 0; jt < 2; ++jt)
                    sacc[it][jt] = __builtin_amdgcn_mfma_f32_16x16x32_bf16(kf[it], qf[jt][s], sacc[it][jt], 0, 0, 0);
        }

        const bool need_mask = (kt >= 2 * qt);
#pragma unroll
        for (int it = 0; it < 4; ++it)
#pragma unroll
            for (int jt = 0; jt < 2; ++jt) {
                const int prow = wq + jt * 16 + l16;
                bf16x4 pb;
                if (need_mask) {
                    const int qrow = q0 + prow;
                    const int kbase = k0 + it * 16 + quad * 4;
#pragma unroll
                    for (int r = 0; r < 4; ++r) {
                        const float e = __ocml_native_exp2_f32(sacc[it][jt][r]);
                        const float p = (kbase + r > qrow) ? 0.f : e;
                        lsum[jt] += p;
                        pb[r] = (bf16)p;
                    }
                } else {
#pragma unroll
                    for (int r = 0; r < 4; ++r) {
                        const float p = __ocml_native_exp2_f32(sacc[it][jt][r]);
                        lsum[jt] += p;
                        pb[r] = (bf16)p;
                    }
                }
                *(bf16x4*)(Ps + prow * 64 +
                           (((it * 2 + (quad >> 1)) ^ (prow & 7)) << 3) + ((quad & 1) << 2)) = pb;
            }

#pragma unroll
        for (int s2 = 0; s2 < 2; ++s2) {
            bf16x8 vf[4], pf[2];
#pragma unroll
            for (int it2 = 0; it2 < 4; ++it2)
                vf[it2] = *(const bf16x8*)(vb_ + offKV[it2][s2]);
#pragma unroll
            for (int jt = 0; jt < 2; ++jt) {
                const int prow = wq + jt * 16 + l16;
                pf[jt] = *(const bf16x8*)(Ps + prow * 64 + (((s2 * 4 + quad) ^ (prow & 7)) << 3));
            }
#pragma unroll
            for (int it2 = 0; it2 < 4; ++it2)
#pragma unroll
                for (int jt = 0; jt < 2; ++jt)
                    oacc[it2][jt] = __builtin_amdgcn_mfma_f32_16x16x32_bf16(vf[it2], pf[jt], oacc[it2][jt], 0, 0, 0);
        }
    }

    float inv[2];
#pragma unroll
    for (int jt = 0; jt < 2; ++jt) {
        float l = lsum[jt];
        l += __shfl_xor(l, 16);
        l += __shfl_xor(l, 32);
        inv[jt] = 1.0f / l;
    }
#pragma unroll
    for (int it2 = 0; it2 < 4; ++it2)
#pragma unroll
        for (int jt = 0; jt < 2; ++jt) {
            bf16x4 ob;
#pragma unroll
            for (int r = 0; r < 4; ++r) ob[r] = (bf16)(oacc[it2][jt][r] * inv[jt]);
            const int qrow = q0 + wq + jt * 16 + l16;
            const int dcol = h * 64 + it2 * 16 + quad * 4;
            *(bf16x4*)&Out[(size_t)(b * T_SEQ + qrow) * 1024 + dcol] = ob;
        }
}

// ---------------------------------------------------------------------------
extern "C" void kernel_launch(void* const* d_in, const int* in_sizes, int n_in,
                              void* d_out, int out_size, void* d_ws, size_t ws_size,
                              hipStream_t stream) {
    const float* x     = (const float*)d_in[0];
    const float* W_qkv = (const float*)d_in[1];
    const float* b_qkv = (const float*)d_in[2];
    const float* W_out = (const float*)d_in[3];
    const float* b_out = (const float*)d_in[4];
    float* out = (float*)d_out;

    char* ws = (char*)d_ws;
    bf16* xb   = (bf16*)ws; ws += (size_t)8192 * 1024 * 2;
    bf16* wtq  = (bf16*)ws; ws += (size_t)3072 * 1024 * 2;
    bf16* wto  = (bf16*)ws; ws += (size_t)1024 * 1024 * 2;
    bf16* qkb  = (bf16*)ws; ws += (size_t)8192 * 2048 * 2;    // Q|K rows
    bf16* vtb  = (bf16*)ws; ws += (size_t)64 * 64 * 2048 * 2; // V^T per bh
    bf16* aout = (bf16*)ws; ws += (size_t)8192 * 1024 * 2;

    cvt_f32_bf16<<<8192, 256, 0, stream>>>(x, xb, 8192 * 1024);
    transpose_cvt<<<dim3(96, 32), dim3(32, 8), 0, stream>>>(W_qkv, wtq, 1024, 3072);
    transpose_cvt<<<dim3(32, 32), dim3(32, 8), 0, stream>>>(W_out, wto, 1024, 1024);

    gemm_bt<true, true><<<dim3(24, 64), 256, 0, stream>>>(
        xb, wtq, b_qkv, (void*)qkb, vtb, 8192, 3072, 1024, 2048);
    attn_kernel<<<dim3(64, 16), 256, 0, stream>>>(qkb, vtb, aout);
    gemm_bt<false, false><<<dim3(8, 64), 256, 0, stream>>>(
        aout, wto, b_out, (void*)out, nullptr, 8192, 1024, 1024, 1024);
}